// Round 1
// baseline (1722.700 us; speedup 1.0000x reference)
//
#include <hip/hip_runtime.h>
#include <math.h>

#define DM 1024
#define DF 1024
#define NE 8

// ---------------- ws layout ----------------
// [0,32)        counts      int[8]
// [64,96)       cursor      int[8]
// [128,160)     seg_start   int[8]
// [256, +128K)  tok_expert  int[2T]
// [+128K,+256K) tok_weight  float[2T]
// [+256K,+384K) gath_tok    int[2T]
// [+384K,+512K) gath_w      float[2T]

__global__ void gate_kernel(const float* __restrict__ x, const float* __restrict__ Wg,
                            const float* __restrict__ bg, int* __restrict__ tok_e,
                            float* __restrict__ tok_w, int* __restrict__ counts, int T) {
    int wid  = threadIdx.x >> 6;
    int lane = threadIdx.x & 63;
    int t = blockIdx.x * 4 + wid;
    if (t >= T) return;
    const float* xt = x + (size_t)t * DM;
    float acc[NE];
#pragma unroll
    for (int e = 0; e < NE; ++e) acc[e] = 0.f;
    for (int d = lane; d < DM; d += 64) {
        float xv = xt[d];
#pragma unroll
        for (int e = 0; e < NE; ++e) acc[e] += xv * Wg[e * DM + d];
    }
#pragma unroll
    for (int e = 0; e < NE; ++e) {
#pragma unroll
        for (int off = 32; off > 0; off >>= 1)
            acc[e] += __shfl_down(acc[e], off, 64);
    }
    if (lane == 0) {
        float l[NE];
#pragma unroll
        for (int e = 0; e < NE; ++e) l[e] = acc[e] + bg[e];
        // top-1: strict > over ascending e  -> lowest index on tie (matches lax.top_k)
        int b0 = 0; float v0 = l[0];
        for (int e = 1; e < NE; ++e) if (l[e] > v0) { v0 = l[e]; b0 = e; }
        int b1 = -1; float v1 = -3.4e38f;
        for (int e = 0; e < NE; ++e) if (e != b0 && l[e] > v1) { v1 = l[e]; b1 = e; }
        float w0 = 1.f / (1.f + expf(-v0));
        float w1 = 1.f / (1.f + expf(-v1));
        tok_e[2 * t]     = b0;  tok_e[2 * t + 1] = b1;
        tok_w[2 * t]     = w0;  tok_w[2 * t + 1] = w1;
        atomicAdd(&counts[b0], 1);
        atomicAdd(&counts[b1], 1);
    }
}

__global__ void scan_kernel(const int* __restrict__ counts, int* __restrict__ seg_start,
                            int* __restrict__ cursor) {
    if (threadIdx.x == 0) {
        int s = 0;
        for (int e = 0; e < NE; ++e) {
            seg_start[e] = s;
            cursor[e]    = s;
            s += counts[e];
        }
    }
}

__global__ void scatter_kernel(const int* __restrict__ tok_e, const float* __restrict__ tok_w,
                               int* __restrict__ cursor, int* __restrict__ gath_tok,
                               float* __restrict__ gath_w, int n_slots) {
    int idx = blockIdx.x * blockDim.x + threadIdx.x;
    if (idx >= n_slots) return;
    int   t = idx >> 1;
    int   e = tok_e[idx];
    float w = tok_w[idx];
    int pos = atomicAdd(&cursor[e], 1);
    gath_tok[pos] = t;
    gath_w[pos]   = w;
}

#define BM 64
#define BN 64
#define BK 32

__global__ __launch_bounds__(256) void expert_gemm(
        const float* __restrict__ X, const float* __restrict__ We,
        const float* __restrict__ be, const int* __restrict__ counts,
        const int* __restrict__ seg_start, const int* __restrict__ gtok,
        const float* __restrict__ gw, float* __restrict__ out) {
    int e   = blockIdx.z;
    int n_e = counts[e];
    int row0 = blockIdx.x * BM;
    if (row0 >= n_e) return;
    int col0 = blockIdx.y * BN;
    int seg  = seg_start[e];

    __shared__ __align__(16) float Xs[BK][BM + 4];  // transposed: Xs[k][row]
    __shared__ __align__(16) float Ws[BK][BN];
    __shared__ int   s_tok[BM];
    __shared__ float s_w[BM];

    int tid = threadIdx.x;
    if (tid < BM) {
        int gr = row0 + tid;
        if (gr < n_e) { s_tok[tid] = gtok[seg + gr]; s_w[tid] = gw[seg + gr]; }
        else          { s_tok[tid] = 0;              s_w[tid] = 0.f; }
    }
    __syncthreads();

    const float* Wbase = We + (size_t)e * DM * DF + col0;
    int tx = tid & 15, ty = tid >> 4;   // tx -> col group, ty -> row group
    float acc[4][4] = {};

    for (int k0 = 0; k0 < DM; k0 += BK) {
        // stage X tile: 64 rows x 32 k, store transposed
#pragma unroll
        for (int i = 0; i < (BM * BK) / 256; ++i) {
            int idx = tid + i * 256;
            int r = idx >> 5, kk = idx & 31;
            Xs[kk][r] = X[(size_t)s_tok[r] * DM + k0 + kk];
        }
        // stage W tile: 32 k x 64 cols
#pragma unroll
        for (int i = 0; i < (BK * BN) / 256; ++i) {
            int idx = tid + i * 256;
            int kk = idx >> 6, c = idx & 63;
            Ws[kk][c] = Wbase[(size_t)(k0 + kk) * DF + c];
        }
        __syncthreads();
#pragma unroll
        for (int kk = 0; kk < BK; ++kk) {
            float4 xv = *(const float4*)&Xs[kk][ty * 4];
            float4 wv = *(const float4*)&Ws[kk][tx * 4];
            acc[0][0] += xv.x * wv.x; acc[0][1] += xv.x * wv.y; acc[0][2] += xv.x * wv.z; acc[0][3] += xv.x * wv.w;
            acc[1][0] += xv.y * wv.x; acc[1][1] += xv.y * wv.y; acc[1][2] += xv.y * wv.z; acc[1][3] += xv.y * wv.w;
            acc[2][0] += xv.z * wv.x; acc[2][1] += xv.z * wv.y; acc[2][2] += xv.z * wv.z; acc[2][3] += xv.z * wv.w;
            acc[3][0] += xv.w * wv.x; acc[3][1] += xv.w * wv.y; acc[3][2] += xv.w * wv.z; acc[3][3] += xv.w * wv.w;
        }
        __syncthreads();
    }

#pragma unroll
    for (int i = 0; i < 4; ++i) {
        int r  = ty * 4 + i;
        int gr = row0 + r;
        if (gr < n_e) {
            int   t = s_tok[r];
            float w = s_w[r];
#pragma unroll
            for (int j = 0; j < 4; ++j) {
                int c = col0 + tx * 4 + j;
                float v = w * (acc[i][j] + be[e * DF + c]);
                atomicAdd(&out[(size_t)t * DF + c], v);
            }
        }
    }
}

extern "C" void kernel_launch(void* const* d_in, const int* in_sizes, int n_in,
                              void* d_out, int out_size, void* d_ws, size_t ws_size,
                              hipStream_t stream) {
    const float* x  = (const float*)d_in[0];
    const float* Wg = (const float*)d_in[1];
    const float* bg = (const float*)d_in[2];
    const float* We = (const float*)d_in[3];
    const float* be = (const float*)d_in[4];
    float* out = (float*)d_out;

    int T = in_sizes[0] / DM;           // 16384
    int n_slots = 2 * T;

    char* ws = (char*)d_ws;
    int*   counts    = (int*)(ws + 0);
    int*   cursor    = (int*)(ws + 64);
    int*   seg_start = (int*)(ws + 128);
    int*   tok_e     = (int*)(ws + 256);
    float* tok_w     = (float*)(ws + 256 + (size_t)n_slots * 4);
    int*   gath_tok  = (int*)(ws + 256 + (size_t)n_slots * 8);
    float* gath_w    = (float*)(ws + 256 + (size_t)n_slots * 12);

    hipMemsetAsync(ws, 0, 256, stream);
    hipMemsetAsync(d_out, 0, (size_t)out_size * sizeof(float), stream);

    gate_kernel<<<(T + 3) / 4, 256, 0, stream>>>(x, Wg, bg, tok_e, tok_w, counts, T);
    scan_kernel<<<1, 64, 0, stream>>>(counts, seg_start, cursor);
    scatter_kernel<<<(n_slots + 255) / 256, 256, 0, stream>>>(tok_e, tok_w, cursor,
                                                              gath_tok, gath_w, n_slots);
    dim3 grid((T + BM - 1) / BM, DF / BN, NE);
    expert_gemm<<<grid, 256, 0, stream>>>(x, We, be, counts, seg_start,
                                          gath_tok, gath_w, out);
}

// Round 2
// 511.344 us; speedup vs baseline: 3.3690x; 3.3690x over previous
//
#include <hip/hip_runtime.h>
#include <math.h>

#define DM 1024
#define DF 1024
#define NE 8

typedef __bf16 bf16x8 __attribute__((ext_vector_type(8)));
typedef float floatx4 __attribute__((ext_vector_type(4)));

// ---------------- ws layout ----------------
// [0, 16M)            WeT   bf16[8][1024][1024]  (transposed: [e][n][k])
// [16M+0,   +32)      counts    int[8]
// [16M+64,  +96)      cursor    int[8]
// [16M+128, +160)     seg_start int[8]
// [16M+256, ...)      tok_e int[2T], tok_w float[2T], gath_tok int[2T], gath_w float[2T]

__global__ void convert_weT(const float* __restrict__ We, __bf16* __restrict__ WeT) {
    int n  = blockIdx.x * 256 + threadIdx.x;
    int kc = blockIdx.y * 8;
    int e  = blockIdx.z;
    const float* src = We + ((size_t)e << 20) + (size_t)kc * DF + n;
    bf16x8 v;
#pragma unroll
    for (int j = 0; j < 8; ++j) v[j] = (__bf16)src[(size_t)j * DF];
    *(bf16x8*)&WeT[((size_t)e << 20) + (size_t)n * DM + kc] = v;
}

__global__ void gate_kernel(const float4* __restrict__ X4, const float4* __restrict__ Wg4,
                            const float* __restrict__ bg, int* __restrict__ tok_e,
                            float* __restrict__ tok_w, int T) {
    int wid  = threadIdx.x >> 6;
    int lane = threadIdx.x & 63;
    int t = blockIdx.x * 4 + wid;
    if (t >= T) return;
    float acc[NE] = {};
#pragma unroll
    for (int c = 0; c < 4; ++c) {
        float4 xv = X4[(size_t)t * 256 + c * 64 + lane];
#pragma unroll
        for (int e = 0; e < NE; ++e) {
            float4 wv = Wg4[e * 256 + c * 64 + lane];
            acc[e] += xv.x * wv.x + xv.y * wv.y + xv.z * wv.z + xv.w * wv.w;
        }
    }
#pragma unroll
    for (int e = 0; e < NE; ++e) {
#pragma unroll
        for (int off = 32; off > 0; off >>= 1)
            acc[e] += __shfl_down(acc[e], off, 64);
    }
    if (lane == 0) {
        float l[NE];
#pragma unroll
        for (int e = 0; e < NE; ++e) l[e] = acc[e] + bg[e];
        int b0 = 0; float v0 = l[0];
        for (int e = 1; e < NE; ++e) if (l[e] > v0) { v0 = l[e]; b0 = e; }
        int b1 = -1; float v1 = -3.4e38f;
        for (int e = 0; e < NE; ++e) if (e != b0 && l[e] > v1) { v1 = l[e]; b1 = e; }
        tok_e[2 * t]     = b0;  tok_e[2 * t + 1] = b1;
        tok_w[2 * t]     = 1.f / (1.f + expf(-v0));
        tok_w[2 * t + 1] = 1.f / (1.f + expf(-v1));
    }
}

__global__ void hist_kernel(const int* __restrict__ tok_e, int* __restrict__ counts, int n) {
    int idx  = blockIdx.x * blockDim.x + threadIdx.x;
    int lane = threadIdx.x & 63;
    int e = (idx < n) ? tok_e[idx] : -1;
#pragma unroll
    for (int ex = 0; ex < NE; ++ex) {
        unsigned long long m = __ballot(e == ex);
        if (m && lane == (__ffsll((long long)m) - 1))
            atomicAdd(&counts[ex], (int)__popcll(m));
    }
}

__global__ void scan_kernel(const int* __restrict__ counts, int* __restrict__ seg_start,
                            int* __restrict__ cursor) {
    if (threadIdx.x == 0) {
        int s = 0;
        for (int e = 0; e < NE; ++e) {
            seg_start[e] = s;
            cursor[e]    = s;
            s += counts[e];
        }
    }
}

__global__ void scatter_kernel(const int* __restrict__ tok_e, const float* __restrict__ tok_w,
                               int* __restrict__ cursor, int* __restrict__ gath_tok,
                               float* __restrict__ gath_w, int n) {
    int idx  = blockIdx.x * blockDim.x + threadIdx.x;
    int lane = threadIdx.x & 63;
    bool act = idx < n;
    int e = act ? tok_e[idx] : -1;
#pragma unroll
    for (int ex = 0; ex < NE; ++ex) {
        unsigned long long m = __ballot(e == ex);
        if (!m) continue;
        int leader = __ffsll((long long)m) - 1;
        int base = 0;
        if (lane == leader) base = atomicAdd(&cursor[ex], (int)__popcll(m));
        base = __shfl(base, leader, 64);
        if (e == ex) {
            int pos = base + (int)__popcll(m & ((1ull << lane) - 1));
            gath_tok[pos] = idx >> 1;
            gath_w[pos]   = tok_w[idx];
        }
    }
}

#define BM 128
#define BN 128
#define BKT 64
#define LDA 72   // lds row stride in bf16 elems (pad 8 -> keeps 16B align, 2-way conflicts only)

__global__ __launch_bounds__(256) void expert_gemm_mfma(
        const float* __restrict__ X, const __bf16* __restrict__ WeT,
        const float* __restrict__ be, const int* __restrict__ counts,
        const int* __restrict__ seg_start, const int* __restrict__ gtok,
        const float* __restrict__ gw, float* __restrict__ out) {
    int e    = blockIdx.z;
    int n_e  = counts[e];
    int row0 = blockIdx.x * BM;
    if (row0 >= n_e) return;
    int col0 = blockIdx.y * BN;
    int seg  = seg_start[e];

    __shared__ __align__(16) __bf16 As[BM * LDA];
    __shared__ __align__(16) __bf16 Bs[BN * LDA];
    __shared__ int   s_tok[BM];
    __shared__ float s_w[BM];

    int tid = threadIdx.x;
    if (tid < BM) {
        int gr = row0 + tid;
        s_tok[tid] = (gr < n_e) ? gtok[seg + gr] : gtok[seg];
        s_w[tid]   = (gr < n_e) ? gw[seg + gr]   : 0.f;
    }
    __syncthreads();

    int lane = tid & 63, wid = tid >> 6;
    int wr = (wid >> 1) * 64, wc = (wid & 1) * 64;
    int m16 = lane & 15, q = lane >> 4;

    floatx4 acc[4][4] = {};

    const __bf16* wbase = WeT + ((size_t)e << 20) + (size_t)col0 * DM;
    int a_r = tid >> 3;          // 32 rows per pass
    int a_k = (tid & 7) * 8;     // 8 k-elems per thread

    for (int k0 = 0; k0 < DM; k0 += BKT) {
        // stage A: gathered rows, fp32 -> bf16
#pragma unroll
        for (int p = 0; p < 4; ++p) {
            int r = a_r + p * 32;
            const float* src = X + (size_t)s_tok[r] * DM + k0 + a_k;
            float4 f0 = *(const float4*)src;
            float4 f1 = *(const float4*)(src + 4);
            bf16x8 v;
            v[0] = (__bf16)f0.x; v[1] = (__bf16)f0.y; v[2] = (__bf16)f0.z; v[3] = (__bf16)f0.w;
            v[4] = (__bf16)f1.x; v[5] = (__bf16)f1.y; v[6] = (__bf16)f1.z; v[7] = (__bf16)f1.w;
            *(bf16x8*)&As[r * LDA + a_k] = v;
        }
        // stage B: WeT rows (already bf16, contiguous in k)
#pragma unroll
        for (int p = 0; p < 4; ++p) {
            int n = a_r + p * 32;
            bf16x8 v = *(const bf16x8*)(wbase + (size_t)n * DM + k0 + a_k);
            *(bf16x8*)&Bs[n * LDA + a_k] = v;
        }
        __syncthreads();
#pragma unroll
        for (int kt = 0; kt < 2; ++kt) {
            bf16x8 af[4], bfr[4];
#pragma unroll
            for (int i = 0; i < 4; ++i)
                af[i] = *(const bf16x8*)&As[(wr + i * 16 + m16) * LDA + kt * 32 + q * 8];
#pragma unroll
            for (int i = 0; i < 4; ++i)
                bfr[i] = *(const bf16x8*)&Bs[(wc + i * 16 + m16) * LDA + kt * 32 + q * 8];
#pragma unroll
            for (int i = 0; i < 4; ++i)
#pragma unroll
                for (int j = 0; j < 4; ++j)
                    acc[i][j] = __builtin_amdgcn_mfma_f32_16x16x32_bf16(af[i], bfr[j], acc[i][j], 0, 0, 0);
        }
        __syncthreads();
    }

    // epilogue: out[t][c] += w * (acc + be[c]) ; C/D layout: col=lane&15, row=q*4+reg
#pragma unroll
    for (int j = 0; j < 4; ++j) {
        int c = col0 + wc + j * 16 + m16;
        float bias = be[e * DF + c];
#pragma unroll
        for (int i = 0; i < 4; ++i) {
#pragma unroll
            for (int rg = 0; rg < 4; ++rg) {
                int rl = wr + i * 16 + q * 4 + rg;
                int gr = row0 + rl;
                if (gr < n_e)
                    atomicAdd(&out[(size_t)s_tok[rl] * DF + c], s_w[rl] * (acc[i][j][rg] + bias));
            }
        }
    }
}

extern "C" void kernel_launch(void* const* d_in, const int* in_sizes, int n_in,
                              void* d_out, int out_size, void* d_ws, size_t ws_size,
                              hipStream_t stream) {
    const float* x  = (const float*)d_in[0];
    const float* Wg = (const float*)d_in[1];
    const float* bg = (const float*)d_in[2];
    const float* We = (const float*)d_in[3];
    const float* be = (const float*)d_in[4];
    float* out = (float*)d_out;

    int T = in_sizes[0] / DM;      // 16384
    int n_slots = 2 * T;

    char* ws = (char*)d_ws;
    const size_t weT_bytes = (size_t)NE * DM * DF * 2;   // 16 MB
    __bf16* WeT      = (__bf16*)ws;
    char*  rt        = ws + weT_bytes;
    int*   counts    = (int*)(rt + 0);
    int*   cursor    = (int*)(rt + 64);
    int*   seg_start = (int*)(rt + 128);
    int*   tok_e     = (int*)(rt + 256);
    float* tok_w     = (float*)(rt + 256 + (size_t)n_slots * 4);
    int*   gath_tok  = (int*)(rt + 256 + (size_t)n_slots * 8);
    float* gath_w    = (float*)(rt + 256 + (size_t)n_slots * 12);

    hipMemsetAsync(rt, 0, 256, stream);
    hipMemsetAsync(d_out, 0, (size_t)out_size * sizeof(float), stream);

    convert_weT<<<dim3(DF / 256, DM / 8, NE), 256, 0, stream>>>(We, WeT);
    gate_kernel<<<(T + 3) / 4, 256, 0, stream>>>((const float4*)x, (const float4*)Wg,
                                                 bg, tok_e, tok_w, T);
    hist_kernel<<<(n_slots + 255) / 256, 256, 0, stream>>>(tok_e, counts, n_slots);
    scan_kernel<<<1, 64, 0, stream>>>(counts, seg_start, cursor);
    scatter_kernel<<<(n_slots + 255) / 256, 256, 0, stream>>>(tok_e, tok_w, cursor,
                                                              gath_tok, gath_w, n_slots);
    dim3 grid((n_slots + BM - 1) / BM, DF / BN, NE);
    expert_gemm_mfma<<<grid, 256, 0, stream>>>(x, WeT, be, counts, seg_start,
                                               gath_tok, gath_w, out);
}

// Round 3
// 454.274 us; speedup vs baseline: 3.7922x; 1.1256x over previous
//
#include <hip/hip_runtime.h>
#include <math.h>

#define DM 1024
#define DF 1024
#define NE 8

typedef __bf16 bf16x8 __attribute__((ext_vector_type(8)));
typedef float floatx4 __attribute__((ext_vector_type(4)));

typedef const __attribute__((address_space(1))) unsigned int* gas_t;
typedef __attribute__((address_space(3))) unsigned int* las_t;

__device__ __forceinline__ void ld_lds16(const void* g, void* l) {
    __builtin_amdgcn_global_load_lds((gas_t)g, (las_t)l, 16, 0, 0);
}

// ---------------- ws layout ----------------
// [0, 33.5M)      Xb   bf16[T][1024]
// [33.5M, 50.3M)  WeT  bf16[8][1024][1024]  ([e][n][k])
// [50.3M, ...)    routing tables

__global__ void convert_x(const float4* __restrict__ X4, __bf16* __restrict__ Xb, int n8) {
    int i = blockIdx.x * 256 + threadIdx.x;
    if (i >= n8) return;
    float4 f0 = X4[2 * i], f1 = X4[2 * i + 1];
    bf16x8 v;
    v[0] = (__bf16)f0.x; v[1] = (__bf16)f0.y; v[2] = (__bf16)f0.z; v[3] = (__bf16)f0.w;
    v[4] = (__bf16)f1.x; v[5] = (__bf16)f1.y; v[6] = (__bf16)f1.z; v[7] = (__bf16)f1.w;
    *(bf16x8*)&Xb[(size_t)i * 8] = v;
}

__global__ void convert_weT(const float* __restrict__ We, __bf16* __restrict__ WeT) {
    int n  = blockIdx.x * 256 + threadIdx.x;
    int kc = blockIdx.y * 8;
    int e  = blockIdx.z;
    const float* src = We + ((size_t)e << 20) + (size_t)kc * DF + n;
    bf16x8 v;
#pragma unroll
    for (int j = 0; j < 8; ++j) v[j] = (__bf16)src[(size_t)j * DF];
    *(bf16x8*)&WeT[((size_t)e << 20) + (size_t)n * DM + kc] = v;
}

__global__ void gate_kernel(const float4* __restrict__ X4, const float4* __restrict__ Wg4,
                            const float* __restrict__ bg, int* __restrict__ tok_e,
                            float* __restrict__ tok_w, int T) {
    int wid  = threadIdx.x >> 6;
    int lane = threadIdx.x & 63;
    int t = blockIdx.x * 4 + wid;
    if (t >= T) return;
    float acc[NE] = {};
#pragma unroll
    for (int c = 0; c < 4; ++c) {
        float4 xv = X4[(size_t)t * 256 + c * 64 + lane];
#pragma unroll
        for (int e = 0; e < NE; ++e) {
            float4 wv = Wg4[e * 256 + c * 64 + lane];
            acc[e] += xv.x * wv.x + xv.y * wv.y + xv.z * wv.z + xv.w * wv.w;
        }
    }
#pragma unroll
    for (int e = 0; e < NE; ++e) {
#pragma unroll
        for (int off = 32; off > 0; off >>= 1)
            acc[e] += __shfl_down(acc[e], off, 64);
    }
    if (lane == 0) {
        float l[NE];
#pragma unroll
        for (int e = 0; e < NE; ++e) l[e] = acc[e] + bg[e];
        int b0 = 0; float v0 = l[0];
        for (int e = 1; e < NE; ++e) if (l[e] > v0) { v0 = l[e]; b0 = e; }
        int b1 = -1; float v1 = -3.4e38f;
        for (int e = 0; e < NE; ++e) if (e != b0 && l[e] > v1) { v1 = l[e]; b1 = e; }
        tok_e[2 * t]     = b0;  tok_e[2 * t + 1] = b1;
        tok_w[2 * t]     = 1.f / (1.f + expf(-v0));
        tok_w[2 * t + 1] = 1.f / (1.f + expf(-v1));
    }
}

__global__ void hist_kernel(const int* __restrict__ tok_e, int* __restrict__ blk_cnt, int n) {
    int b = blockIdx.x, tid = threadIdx.x;
    int idx  = b * 256 + tid;
    int lane = tid & 63, w = tid >> 6;
    int e = (idx < n) ? tok_e[idx] : -1;
    __shared__ int wc[4][NE];
#pragma unroll
    for (int ex = 0; ex < NE; ++ex) {
        unsigned long long m = __ballot(e == ex);
        if (lane == 0) wc[w][ex] = (int)__popcll(m);
    }
    __syncthreads();
    if (tid < NE) blk_cnt[b * NE + tid] = wc[0][tid] + wc[1][tid] + wc[2][tid] + wc[3][tid];
}

__global__ void scan_kernel(const int* __restrict__ blk_cnt, int* __restrict__ blk_base,
                            int* __restrict__ seg_start, int* __restrict__ counts, int NB) {
    __shared__ int c[2048];
    __shared__ int tot[NE], base[NE];
    int tid = threadIdx.x;
    for (int i = tid; i < NB * NE; i += 256) c[i] = blk_cnt[i];
    __syncthreads();
    if (tid < NE) {
        int s = 0;
        for (int b = 0; b < NB; ++b) s += c[b * NE + tid];
        tot[tid] = s;
        counts[tid] = s;
    }
    __syncthreads();
    if (tid == 0) {
        int s = 0;
        for (int e = 0; e < NE; ++e) { base[e] = s; s += tot[e]; }
    }
    __syncthreads();
    if (tid < NE) {
        int run = base[tid];
        for (int b = 0; b < NB; ++b) { int v = c[b * NE + tid]; c[b * NE + tid] = run; run += v; }
        seg_start[tid] = base[tid];
    }
    __syncthreads();
    for (int i = tid; i < NB * NE; i += 256) blk_base[i] = c[i];
}

__global__ void scatter_kernel(const int* __restrict__ tok_e, const float* __restrict__ tok_w,
                               const int* __restrict__ blk_base, int* __restrict__ gath_tok,
                               float* __restrict__ gath_w, int n) {
    int b = blockIdx.x, tid = threadIdx.x;
    int idx  = b * 256 + tid;
    int lane = tid & 63, w = tid >> 6;
    bool act = idx < n;
    int e = act ? tok_e[idx] : -1;
    __shared__ int wc[4][NE], wb[4][NE];
    int myrank = 0;
#pragma unroll
    for (int ex = 0; ex < NE; ++ex) {
        unsigned long long m = __ballot(e == ex);
        if (lane == 0) wc[w][ex] = (int)__popcll(m);
        if (e == ex) myrank = (int)__popcll(m & ((1ull << lane) - 1ull));
    }
    __syncthreads();
    if (tid < NE) {
        int run = blk_base[b * NE + tid];
#pragma unroll
        for (int wv = 0; wv < 4; ++wv) { wb[wv][tid] = run; run += wc[wv][tid]; }
    }
    __syncthreads();
    if (act) {
        int pos = wb[w][e] + myrank;
        gath_tok[pos] = idx >> 1;
        gath_w[pos]   = tok_w[idx];
    }
}

#define BM 128
#define BN 128
#define BKT 64

__global__ __launch_bounds__(256) void expert_gemm_mfma(
        const __bf16* __restrict__ Xb, const __bf16* __restrict__ WeT,
        const float* __restrict__ be, const int* __restrict__ counts,
        const int* __restrict__ seg_start, const int* __restrict__ gtok,
        const float* __restrict__ gw, float* __restrict__ out) {
    int e    = blockIdx.z;
    int n_e  = counts[e];
    int row0 = blockIdx.x * BM;
    if (n_e == 0 || row0 >= n_e) return;
    int col0 = blockIdx.y * BN;
    int seg  = seg_start[e];

    // swizzled lane-linear layout: elem(r,k) at r*64 + ((k>>3)^(r&7))*8 + (k&7)
    __shared__ __align__(16) __bf16 As[BM * BKT];
    __shared__ __align__(16) __bf16 Bs[BN * BKT];
    __shared__ int   s_tok[BM];
    __shared__ float s_w[BM];

    int tid = threadIdx.x;
    if (tid < BM) {
        int gr = row0 + tid;
        s_tok[tid] = (gr < n_e) ? gtok[seg + gr] : gtok[seg];
        s_w[tid]   = (gr < n_e) ? gw[seg + gr]   : 0.f;
    }
    __syncthreads();

    int lane = tid & 63, w = tid >> 6;
    int lr = lane >> 3;              // row-within-8
    int kc = (lane & 7) ^ lr;        // XOR-swizzled k-chunk

    const __bf16* aptr[4];
    const __bf16* bptr[4];
#pragma unroll
    for (int p = 0; p < 4; ++p) {
        int r = p * 32 + w * 8 + lr;
        aptr[p] = Xb + (size_t)s_tok[r] * DM + kc * 8;
        bptr[p] = WeT + ((size_t)e << 20) + (size_t)(col0 + r) * DM + kc * 8;
    }

    int wr = (w >> 1) * 64, wcc = (w & 1) * 64;
    int m16 = lane & 15, q = lane >> 4;
    int rsw = m16 & 7;

    floatx4 acc[4][4] = {};

    for (int k0 = 0; k0 < DM; k0 += BKT) {
#pragma unroll
        for (int p = 0; p < 4; ++p)
            ld_lds16(aptr[p] + k0, &As[(p * 4 + w) * 512]);
#pragma unroll
        for (int p = 0; p < 4; ++p)
            ld_lds16(bptr[p] + k0, &Bs[(p * 4 + w) * 512]);
        __syncthreads();
#pragma unroll
        for (int kt = 0; kt < 2; ++kt) {
            bf16x8 af[4], bfr[4];
#pragma unroll
            for (int i = 0; i < 4; ++i)
                af[i] = *(const bf16x8*)&As[(wr + i * 16 + m16) * 64 + ((kt * 4 + q) ^ rsw) * 8];
#pragma unroll
            for (int i = 0; i < 4; ++i)
                bfr[i] = *(const bf16x8*)&Bs[(wcc + i * 16 + m16) * 64 + ((kt * 4 + q) ^ rsw) * 8];
#pragma unroll
            for (int i = 0; i < 4; ++i)
#pragma unroll
                for (int j = 0; j < 4; ++j)
                    acc[i][j] = __builtin_amdgcn_mfma_f32_16x16x32_bf16(af[i], bfr[j], acc[i][j], 0, 0, 0);
        }
        __syncthreads();
    }

#pragma unroll
    for (int j = 0; j < 4; ++j) {
        int c = col0 + wcc + j * 16 + m16;
        float bias = be[e * DF + c];
#pragma unroll
        for (int i = 0; i < 4; ++i) {
#pragma unroll
            for (int rg = 0; rg < 4; ++rg) {
                int rl = wr + i * 16 + q * 4 + rg;
                int gr = row0 + rl;
                if (gr < n_e)
                    atomicAdd(&out[(size_t)s_tok[rl] * DF + c], s_w[rl] * (acc[i][j][rg] + bias));
            }
        }
    }
}

extern "C" void kernel_launch(void* const* d_in, const int* in_sizes, int n_in,
                              void* d_out, int out_size, void* d_ws, size_t ws_size,
                              hipStream_t stream) {
    const float* x  = (const float*)d_in[0];
    const float* Wg = (const float*)d_in[1];
    const float* bg = (const float*)d_in[2];
    const float* We = (const float*)d_in[3];
    const float* be = (const float*)d_in[4];
    float* out = (float*)d_out;

    int T = in_sizes[0] / DM;
    int n_slots = 2 * T;
    int NB = (n_slots + 255) / 256;

    char* ws = (char*)d_ws;
    size_t xb_bytes  = (size_t)T * DM * 2;
    size_t weT_bytes = (size_t)NE * DM * DF * 2;
    __bf16* Xb  = (__bf16*)ws;
    __bf16* WeT = (__bf16*)(ws + xb_bytes);
    char* rt = ws + xb_bytes + weT_bytes;
    int*   seg_start = (int*)(rt + 0);
    int*   counts    = (int*)(rt + 64);
    int*   blk_cnt   = (int*)(rt + 128);
    int*   blk_base  = (int*)(rt + 128 + 2048 * 4);
    int*   tok_e     = (int*)(rt + 128 + 2 * 2048 * 4);
    float* tok_w     = (float*)((char*)tok_e + (size_t)n_slots * 4);
    int*   gath_tok  = (int*)((char*)tok_w + (size_t)n_slots * 4);
    float* gath_w    = (float*)((char*)gath_tok + (size_t)n_slots * 4);

    hipMemsetAsync(d_out, 0, (size_t)out_size * sizeof(float), stream);

    convert_x<<<(T * DM / 8 + 255) / 256, 256, 0, stream>>>((const float4*)x, Xb, T * DM / 8);
    convert_weT<<<dim3(DF / 256, DM / 8, NE), 256, 0, stream>>>(We, WeT);
    gate_kernel<<<(T + 3) / 4, 256, 0, stream>>>((const float4*)x, (const float4*)Wg,
                                                 bg, tok_e, tok_w, T);
    hist_kernel<<<NB, 256, 0, stream>>>(tok_e, blk_cnt, n_slots);
    scan_kernel<<<1, 256, 0, stream>>>(blk_cnt, blk_base, seg_start, counts, NB);
    scatter_kernel<<<NB, 256, 0, stream>>>(tok_e, tok_w, blk_base, gath_tok, gath_w, n_slots);
    dim3 grid((n_slots + BM - 1) / BM, DF / BN, NE);
    expert_gemm_mfma<<<grid, 256, 0, stream>>>(Xb, WeT, be, counts, seg_start,
                                               gath_tok, gath_w, out);
}

// Round 4
// 389.386 us; speedup vs baseline: 4.4241x; 1.1666x over previous
//
#include <hip/hip_runtime.h>
#include <math.h>

#define DM 1024
#define DF 1024
#define NE 8
#define NBIN 16          // (pass, expert) bins: bin = p*8 + e
#define MAXT 136         // max worklist tiles per pass
#define BM 128
#define BN 128
#define BKT 64

typedef __bf16 bf16x8 __attribute__((ext_vector_type(8)));
typedef __bf16 bf16x4 __attribute__((ext_vector_type(4)));
typedef float floatx4 __attribute__((ext_vector_type(4)));

typedef const __attribute__((address_space(1))) unsigned int* gas_t;
typedef __attribute__((address_space(3))) unsigned int* las_t;

__device__ __forceinline__ void ld_lds16(const void* g, void* l) {
    __builtin_amdgcn_global_load_lds((gas_t)g, (las_t)l, 16, 0, 0);
}

// ---------------- ws layout ----------------
// [0, 33.5M)      Xb   bf16[T][1024]
// [33.5M, 50.3M)  WeT  bf16[8][1024][1024]  ([e][n][k])
// [50.3M, ...)    routing: ntiles[2], wl0/wl1 (int4[136] each), blk_cnt, blk_base,
//                 tok_e, tok_w, gath_tok, gath_w

__global__ void convert_weT(const float* __restrict__ We, __bf16* __restrict__ WeT) {
    int n  = blockIdx.x * 256 + threadIdx.x;
    int kc = blockIdx.y * 8;
    int e  = blockIdx.z;
    const float* src = We + ((size_t)e << 20) + (size_t)kc * DF + n;
    bf16x8 v;
#pragma unroll
    for (int j = 0; j < 8; ++j) v[j] = (__bf16)src[(size_t)j * DF];
    *(bf16x8*)&WeT[((size_t)e << 20) + (size_t)n * DM + kc] = v;
}

// fused: gate logits + top-2 + sigmoid + X -> bf16 conversion (X already in regs)
__global__ void gate_kernel(const float4* __restrict__ X4, const float4* __restrict__ Wg4,
                            const float* __restrict__ bg, int* __restrict__ tok_e,
                            float* __restrict__ tok_w, __bf16* __restrict__ Xb, int T) {
    int wid  = threadIdx.x >> 6;
    int lane = threadIdx.x & 63;
    int t = blockIdx.x * 4 + wid;
    if (t >= T) return;
    float acc[NE] = {};
    float4 xs[4];
#pragma unroll
    for (int c = 0; c < 4; ++c) {
        float4 xv = X4[(size_t)t * 256 + c * 64 + lane];
        xs[c] = xv;
#pragma unroll
        for (int e = 0; e < NE; ++e) {
            float4 wv = Wg4[e * 256 + c * 64 + lane];
            acc[e] += xv.x * wv.x + xv.y * wv.y + xv.z * wv.z + xv.w * wv.w;
        }
    }
    // convert this token's X row to bf16 (coalesced 8B stores)
#pragma unroll
    for (int c = 0; c < 4; ++c) {
        bf16x4 v;
        v[0] = (__bf16)xs[c].x; v[1] = (__bf16)xs[c].y;
        v[2] = (__bf16)xs[c].z; v[3] = (__bf16)xs[c].w;
        *(bf16x4*)&Xb[(size_t)t * DM + c * 256 + lane * 4] = v;
    }
#pragma unroll
    for (int e = 0; e < NE; ++e) {
#pragma unroll
        for (int off = 32; off > 0; off >>= 1)
            acc[e] += __shfl_down(acc[e], off, 64);
    }
    if (lane == 0) {
        float l[NE];
#pragma unroll
        for (int e = 0; e < NE; ++e) l[e] = acc[e] + bg[e];
        int b0 = 0; float v0 = l[0];
        for (int e = 1; e < NE; ++e) if (l[e] > v0) { v0 = l[e]; b0 = e; }
        int b1 = -1; float v1 = -3.4e38f;
        for (int e = 0; e < NE; ++e) if (e != b0 && l[e] > v1) { v1 = l[e]; b1 = e; }
        tok_e[2 * t]     = b0;  tok_e[2 * t + 1] = b1;
        tok_w[2 * t]     = 1.f / (1.f + expf(-v0));
        tok_w[2 * t + 1] = 1.f / (1.f + expf(-v1));
    }
}

// per-block 16-bin histogram via ballots (no global atomics)
__global__ void hist_kernel(const int* __restrict__ tok_e, int* __restrict__ blk_cnt, int n) {
    int b = blockIdx.x, tid = threadIdx.x;
    int idx  = b * 256 + tid;
    int lane = tid & 63, w = tid >> 6;
    int bin = (idx < n) ? ((idx & 1) * NE + tok_e[idx]) : -1;
    __shared__ int wc[4][NBIN];
#pragma unroll
    for (int bx = 0; bx < NBIN; ++bx) {
        unsigned long long m = __ballot(bin == bx);
        if (lane == 0) wc[w][bx] = (int)__popcll(m);
    }
    __syncthreads();
    if (tid < NBIN) blk_cnt[b * NBIN + tid] = wc[0][tid] + wc[1][tid] + wc[2][tid] + wc[3][tid];
}

// scan over blocks + bins, and build the two GEMM worklists
__global__ void scan_kernel(const int* __restrict__ blk_cnt, int* __restrict__ blk_base,
                            int4* __restrict__ wl, int* __restrict__ ntiles, int NB) {
    __shared__ int c[2048];
    __shared__ int tot[NBIN], base[NBIN];
    int tid = threadIdx.x;
    for (int i = tid; i < NB * NBIN; i += 256) c[i] = blk_cnt[i];
    __syncthreads();
    if (tid < NBIN) {
        int s = 0;
        for (int b = 0; b < NB; ++b) s += c[b * NBIN + tid];
        tot[tid] = s;
    }
    __syncthreads();
    if (tid == 0) {
        int s = 0;
        for (int b = 0; b < NBIN; ++b) { base[b] = s; s += tot[b]; }
    }
    __syncthreads();
    if (tid < NBIN) {
        int run = base[tid];
        for (int b = 0; b < NB; ++b) { int v = c[b * NBIN + tid]; c[b * NBIN + tid] = run; run += v; }
    }
    __syncthreads();
    for (int i = tid; i < NB * NBIN; i += 256) blk_base[i] = c[i];
    if (tid == 0) {
        for (int p = 0; p < 2; ++p) {
            int nt = 0;
            for (int e = 0; e < NE; ++e) {
                int bin = p * NE + e;
                int cnt = tot[bin], sg = base[bin];
                for (int r0 = 0; r0 < cnt; r0 += BM)
                    wl[p * MAXT + nt++] = make_int4(e, r0, sg, cnt);
            }
            ntiles[p] = nt;
        }
    }
}

// deterministic rank-based scatter into 16 bins (no global atomics)
__global__ void scatter_kernel(const int* __restrict__ tok_e, const float* __restrict__ tok_w,
                               const int* __restrict__ blk_base, int* __restrict__ gath_tok,
                               float* __restrict__ gath_w, int n) {
    int b = blockIdx.x, tid = threadIdx.x;
    int idx  = b * 256 + tid;
    int lane = tid & 63, w = tid >> 6;
    bool act = idx < n;
    int bin = act ? ((idx & 1) * NE + tok_e[idx]) : -1;
    __shared__ int wc[4][NBIN], wb[4][NBIN];
    int myrank = 0;
#pragma unroll
    for (int bx = 0; bx < NBIN; ++bx) {
        unsigned long long m = __ballot(bin == bx);
        if (lane == 0) wc[w][bx] = (int)__popcll(m);
        if (bin == bx) myrank = (int)__popcll(m & ((1ull << lane) - 1ull));
    }
    __syncthreads();
    if (tid < NBIN) {
        int run = blk_base[b * NBIN + tid];
#pragma unroll
        for (int wv = 0; wv < 4; ++wv) { wb[wv][tid] = run; run += wc[wv][tid]; }
    }
    __syncthreads();
    if (act) {
        int pos = wb[w][bin] + myrank;
        gath_tok[pos] = idx >> 1;
        gath_w[pos]   = tok_w[idx];
    }
}

template <bool ACC>
__global__ __launch_bounds__(256) void expert_gemm_mfma(
        const __bf16* __restrict__ Xb, const __bf16* __restrict__ WeT,
        const float* __restrict__ be, const int4* __restrict__ wl,
        const int* __restrict__ ntiles, const int* __restrict__ gtok,
        const float* __restrict__ gw, float* __restrict__ out) {
    if ((int)blockIdx.x >= ntiles[0]) return;
    int4 ent = wl[blockIdx.x];
    int e = ent.x, row0 = ent.y, seg = ent.z, n_e = ent.w;
    int col0 = blockIdx.y * BN;

    // swizzled lane-linear layout: elem(r,k) at r*64 + ((k>>3)^(r&7))*8 + (k&7)
    __shared__ __align__(16) __bf16 As[BM * BKT];
    __shared__ __align__(16) __bf16 Bs[BN * BKT];
    __shared__ int   s_tok[BM];
    __shared__ float s_w[BM];

    int tid = threadIdx.x;
    if (tid < BM) {
        int gr = row0 + tid;
        s_tok[tid] = (gr < n_e) ? gtok[seg + gr] : gtok[seg];
        s_w[tid]   = (gr < n_e) ? gw[seg + gr]   : 0.f;
    }
    __syncthreads();

    int lane = tid & 63, w = tid >> 6;
    int lr = lane >> 3;              // row-within-8
    int kc = (lane & 7) ^ lr;        // XOR-swizzled k-chunk

    const __bf16* aptr[4];
    const __bf16* bptr[4];
#pragma unroll
    for (int p = 0; p < 4; ++p) {
        int r = p * 32 + w * 8 + lr;
        aptr[p] = Xb + (size_t)s_tok[r] * DM + kc * 8;
        bptr[p] = WeT + ((size_t)e << 20) + (size_t)(col0 + r) * DM + kc * 8;
    }

    int wr = (w >> 1) * 64, wcc = (w & 1) * 64;
    int m16 = lane & 15, q = lane >> 4;
    int rsw = m16 & 7;

    floatx4 acc[4][4] = {};

    for (int k0 = 0; k0 < DM; k0 += BKT) {
#pragma unroll
        for (int p = 0; p < 4; ++p)
            ld_lds16(aptr[p] + k0, &As[(p * 4 + w) * 512]);
#pragma unroll
        for (int p = 0; p < 4; ++p)
            ld_lds16(bptr[p] + k0, &Bs[(p * 4 + w) * 512]);
        __syncthreads();
#pragma unroll
        for (int kt = 0; kt < 2; ++kt) {
            bf16x8 af[4], bfr[4];
#pragma unroll
            for (int i = 0; i < 4; ++i)
                af[i] = *(const bf16x8*)&As[(wr + i * 16 + m16) * 64 + ((kt * 4 + q) ^ rsw) * 8];
#pragma unroll
            for (int i = 0; i < 4; ++i)
                bfr[i] = *(const bf16x8*)&Bs[(wcc + i * 16 + m16) * 64 + ((kt * 4 + q) ^ rsw) * 8];
#pragma unroll
            for (int i = 0; i < 4; ++i)
#pragma unroll
                for (int j = 0; j < 4; ++j)
                    acc[i][j] = __builtin_amdgcn_mfma_f32_16x16x32_bf16(af[i], bfr[j], acc[i][j], 0, 0, 0);
        }
        __syncthreads();
    }

    // epilogue: plain stores (pass 0) or unique-writer read-add-store (pass 1)
    // C/D layout: col=lane&15, row=q*4+reg
#pragma unroll
    for (int j = 0; j < 4; ++j) {
        int c = col0 + wcc + j * 16 + m16;
        float bias = be[e * DF + c];
#pragma unroll
        for (int i = 0; i < 4; ++i) {
#pragma unroll
            for (int rg = 0; rg < 4; ++rg) {
                int rl = wr + i * 16 + q * 4 + rg;
                int gr = row0 + rl;
                if (gr < n_e) {
                    size_t o = (size_t)s_tok[rl] * DF + c;
                    float v = s_w[rl] * (acc[i][j][rg] + bias);
                    if (ACC) out[o] += v;
                    else     out[o] = v;
                }
            }
        }
    }
}

extern "C" void kernel_launch(void* const* d_in, const int* in_sizes, int n_in,
                              void* d_out, int out_size, void* d_ws, size_t ws_size,
                              hipStream_t stream) {
    const float* x  = (const float*)d_in[0];
    const float* Wg = (const float*)d_in[1];
    const float* bg = (const float*)d_in[2];
    const float* We = (const float*)d_in[3];
    const float* be = (const float*)d_in[4];
    float* out = (float*)d_out;

    int T = in_sizes[0] / DM;
    int n_slots = 2 * T;
    int NB = (n_slots + 255) / 256;

    char* ws = (char*)d_ws;
    size_t xb_bytes  = (size_t)T * DM * 2;
    size_t weT_bytes = (size_t)NE * DM * DF * 2;
    __bf16* Xb  = (__bf16*)ws;
    __bf16* WeT = (__bf16*)(ws + xb_bytes);
    char* rt = ws + xb_bytes + weT_bytes;
    int*   ntiles    = (int*)(rt + 0);
    int4*  wl        = (int4*)(rt + 64);                     // 2 * 136 int4
    int*   blk_cnt   = (int*)(rt + 64 + 2 * MAXT * 16);
    int*   blk_base  = (int*)((char*)blk_cnt + (size_t)NB * NBIN * 4);
    int*   tok_e     = (int*)((char*)blk_base + (size_t)NB * NBIN * 4);
    float* tok_w     = (float*)((char*)tok_e + (size_t)n_slots * 4);
    int*   gath_tok  = (int*)((char*)tok_w + (size_t)n_slots * 4);
    float* gath_w    = (float*)((char*)gath_tok + (size_t)n_slots * 4);

    convert_weT<<<dim3(DF / 256, DM / 8, NE), 256, 0, stream>>>(We, WeT);
    gate_kernel<<<(T + 3) / 4, 256, 0, stream>>>((const float4*)x, (const float4*)Wg,
                                                 bg, tok_e, tok_w, Xb, T);
    hist_kernel<<<NB, 256, 0, stream>>>(tok_e, blk_cnt, n_slots);
    scan_kernel<<<1, 256, 0, stream>>>(blk_cnt, blk_base, wl, ntiles, NB);
    scatter_kernel<<<NB, 256, 0, stream>>>(tok_e, tok_w, blk_base, gath_tok, gath_w, n_slots);

    dim3 grid(MAXT, DF / BN);
    expert_gemm_mfma<false><<<grid, 256, 0, stream>>>(Xb, WeT, be, wl, ntiles,
                                                      gath_tok, gath_w, out);
    expert_gemm_mfma<true><<<grid, 256, 0, stream>>>(Xb, WeT, be, wl + MAXT, ntiles + 1,
                                                     gath_tok, gath_w, out);
}